// Round 12
// baseline (1044.373 us; speedup 1.0000x reference)
//
#include <hip/hip_runtime.h>
#include <hip/hip_cooperative_groups.h>

namespace cg = cooperative_groups;

#define D 128

typedef __attribute__((ext_vector_type(8))) short bf16x8;          // 8 bf16 (4 VGPRs)
typedef __attribute__((ext_vector_type(4))) float f32x4;           // MFMA accum / NT loads
typedef __attribute__((ext_vector_type(4))) unsigned short u16x4;  // 4 bf16

__device__ inline unsigned short f2bf(float f) {
    union { float f; unsigned u; } v; v.f = f;
    unsigned r = v.u + 0x7FFF + ((v.u >> 16) & 1);   // RNE
    return (unsigned short)(r >> 16);
}
__device__ inline float bf2f(unsigned short h) {
    union { unsigned u; float f; } v; v.u = ((unsigned)h) << 16; return v.f;
}

// ---------------- aggregate phase: agg = mean_dst relu(feat[src] + ea[eid]) ----------------
// Grid-stride by wave: 1 node/wave, half-wave per edge, 8 edges in flight.
// All shfl sites exec-uniform (R5 lesson): uniform branch conditions; odd tail runs
// all 64 lanes with accumulation guarded to half 0 (no shfl inside the guard).

__device__ void agg_phase(const unsigned short* __restrict__ featb,
                          const float* __restrict__ ea,
                          const int* __restrict__ off,
                          const long long* __restrict__ pairs,
                          unsigned short* __restrict__ aggb, int N) {
    int t = threadIdx.x & 63;
    int half = t >> 5, l32 = t & 31;
    int gw = (blockIdx.x * 256 + threadIdx.x) >> 6;
    int TW = (gridDim.x * 256) >> 6;

    for (int nd = gw; nd < N; nd += TW) {
        int s = off[nd], e = off[nd + 1];
        float a0 = 0.f, a1 = 0.f, a2 = 0.f, a3 = 0.f;

        for (int b = s; b < e; b += 64) {
            int cnt = min(64, e - b);
            long long prl = (b + t < e) ? __builtin_nontemporal_load(&pairs[b + t]) : 0LL;
            int psrc = (int)prl;           // src node
            int peid = (int)(prl >> 32);   // edge id

            auto fetch = [&](int idx, f32x4& ev, u16x4& xv) {
                int sidx = __shfl(psrc, idx, 64);
                int eidx = __shfl(peid, idx, 64);
                ev = __builtin_nontemporal_load(
                    reinterpret_cast<const f32x4*>(&ea[(size_t)eidx * D + l32 * 4]));
                xv = *reinterpret_cast<const u16x4*>(&featb[(size_t)sidx * D + l32 * 4]);
            };
            auto accum = [&](const f32x4& ev, const u16x4& xv) {
                a0 += fmaxf(bf2f(xv[0]) + ev[0], 0.f);
                a1 += fmaxf(bf2f(xv[1]) + ev[1], 0.f);
                a2 += fmaxf(bf2f(xv[2]) + ev[2], 0.f);
                a3 += fmaxf(bf2f(xv[3]) + ev[3], 0.f);
            };

            int p = 0;
            for (; p + 8 <= cnt; p += 8) {          // uniform condition
                f32x4 e0, e1, e2, e3; u16x4 x0, x1, x2, x3;
                fetch(p + half, e0, x0);
                fetch(p + 2 + half, e1, x1);
                fetch(p + 4 + half, e2, x2);
                fetch(p + 6 + half, e3, x3);
                accum(e0, x0); accum(e1, x1); accum(e2, x2); accum(e3, x3);
            }
            if (p + 4 <= cnt) {                     // uniform
                f32x4 e0, e1; u16x4 x0, x1;
                fetch(p + half, e0, x0);
                fetch(p + 2 + half, e1, x1);
                accum(e0, x0); accum(e1, x1);
                p += 4;
            }
            if (p + 2 <= cnt) {                     // uniform
                f32x4 e0; u16x4 x0;
                fetch(p + half, e0, x0);
                accum(e0, x0);
                p += 2;
            }
            if (p < cnt) {                          // uniform; last odd edge
                f32x4 e0; u16x4 x0;
                fetch(p, e0, x0);                   // all 64 lanes shfl/load
                if (half == 0) accum(e0, x0);       // no shfl inside guard
            }
        }

        a0 += __shfl_xor(a0, 32, 64);
        a1 += __shfl_xor(a1, 32, 64);
        a2 += __shfl_xor(a2, 32, 64);
        a3 += __shfl_xor(a3, 32, 64);
        int deg = e - s;
        float inv = 1.f / (float)(deg > 0 ? deg : 1);
        if (half == 0) {
            u16x4 r;
            r[0] = f2bf(a0 * inv); r[1] = f2bf(a1 * inv);
            r[2] = f2bf(a2 * inv); r[3] = f2bf(a3 * inv);
            *reinterpret_cast<u16x4*>(&aggb[(size_t)nd * D + l32 * 4]) = r;
        }
    }
}

// ---------------- GEMM phase: out = act([A1|A2](Nx256) @ Wt^T + bias) ----------------
// 4 waves/block; wave w owns cols [32w,32w+32) as 2 16-col tiles; B-frags persist in
// registers. Grid-stride over 32-row M-tiles; stores guarded by row<N.

__device__ void gemm_phase(const unsigned short* __restrict__ A1,
                           const unsigned short* __restrict__ A2,
                           const unsigned short* __restrict__ Wt,
                           const float* __restrict__ bias,
                           float* __restrict__ outf,
                           unsigned short* __restrict__ outb,
                           int MT, int N, int RELU, int OBF) {
    int tid = threadIdx.x;
    int w = tid >> 6;
    int l = tid & 63;
    int lr = l & 15;
    int lg = l >> 4;
    int c0 = w * 32;

    bf16x8 bfr[2][8];
    #pragma unroll
    for (int t = 0; t < 2; ++t)
        #pragma unroll
        for (int kc = 0; kc < 8; ++kc)
            bfr[t][kc] = *reinterpret_cast<const bf16x8*>(
                &Wt[(size_t)(c0 + t * 16 + lr) * 256 + kc * 32 + lg * 8]);

    for (int mt = blockIdx.x; mt < MT; mt += gridDim.x) {
        int r0 = mt * 32;
        f32x4 acc[2][2];
        #pragma unroll
        for (int tr = 0; tr < 2; ++tr)
            #pragma unroll
            for (int tc = 0; tc < 2; ++tc) acc[tr][tc] = {0.f, 0.f, 0.f, 0.f};

        #pragma unroll
        for (int kc = 0; kc < 8; ++kc) {
            const unsigned short* Ap = (kc < 4) ? A1 : A2;
            int k = (kc & 3) * 32 + lg * 8;
            bf16x8 af0 = *reinterpret_cast<const bf16x8*>(&Ap[(size_t)(r0 + lr) * D + k]);
            bf16x8 af1 = *reinterpret_cast<const bf16x8*>(&Ap[(size_t)(r0 + 16 + lr) * D + k]);
            acc[0][0] = __builtin_amdgcn_mfma_f32_16x16x32_bf16(af0, bfr[0][kc], acc[0][0], 0, 0, 0);
            acc[1][0] = __builtin_amdgcn_mfma_f32_16x16x32_bf16(af1, bfr[0][kc], acc[1][0], 0, 0, 0);
            acc[0][1] = __builtin_amdgcn_mfma_f32_16x16x32_bf16(af0, bfr[1][kc], acc[0][1], 0, 0, 0);
            acc[1][1] = __builtin_amdgcn_mfma_f32_16x16x32_bf16(af1, bfr[1][kc], acc[1][1], 0, 0, 0);
        }

        #pragma unroll
        for (int tc = 0; tc < 2; ++tc) {
            int col = c0 + tc * 16 + lr;
            float bv = bias[col];
            #pragma unroll
            for (int tr = 0; tr < 2; ++tr) {
                #pragma unroll
                for (int r = 0; r < 4; ++r) {
                    int row = r0 + tr * 16 + lg * 4 + r;
                    if (row < N) {
                        float v = acc[tr][tc][r] + bv;
                        if (RELU) v = fmaxf(v, 0.f);
                        if (OBF) outb[(size_t)row * D + col] = f2bf(v);
                        else outf[(size_t)row * D + col] = v;
                    }
                }
            }
        }
    }
}

// ---------------- the whole pipeline as one cooperative kernel ----------------

__global__ __launch_bounds__(256, 4) void mega_kernel(
    const float* __restrict__ x, const int* __restrict__ src,
    const int* __restrict__ dst, const float* __restrict__ ea,
    const float* __restrict__ W1l, const float* __restrict__ b1l,
    const float* __restrict__ W1r, const float* __restrict__ W2l,
    const float* __restrict__ b2l, const float* __restrict__ W2r,
    int* __restrict__ cnt, int* __restrict__ bsum, int* __restrict__ off,
    int* __restrict__ cursor, long long* __restrict__ pairs,
    unsigned short* __restrict__ xb, unsigned short* __restrict__ z1b,
    unsigned short* __restrict__ aggb,
    unsigned short* __restrict__ Wt1, unsigned short* __restrict__ Wt2,
    float* __restrict__ out, int N, int E, int NB, int MT) {
    cg::grid_group g = cg::this_grid();
    __shared__ int wsh[4];
    int tid = threadIdx.x;
    int gtid = blockIdx.x * 256 + tid;
    int gsz = gridDim.x * 256;

    // P1: x -> bf16 | count dst | W transpose (cnt zeroed by host memset)
    int n4 = N * D / 4;
    for (int i = gtid; i < n4; i += gsz) {
        float4 v = reinterpret_cast<const float4*>(x)[i];
        ushort4 r;
        r.x = f2bf(v.x); r.y = f2bf(v.y); r.z = f2bf(v.z); r.w = f2bf(v.w);
        reinterpret_cast<ushort4*>(xb)[i] = r;
    }
    for (int e = gtid; e < E; e += gsz) atomicAdd(&cnt[dst[e]], 1);
    for (int i = gtid; i < 128 * 256; i += gsz) {
        int c = i >> 8, k = i & 255;
        float v1 = (k < 128) ? W1l[k * 128 + c] : W1r[(k - 128) * 128 + c];
        float v2 = (k < 128) ? W2l[k * 128 + c] : W2r[(k - 128) * 128 + c];
        Wt1[c * 256 + k] = f2bf(v1);
        Wt2[c * 256 + k] = f2bf(v2);
    }
    g.sync();

    // P2: per-1024-chunk sums
    for (int b = blockIdx.x; b < NB; b += gridDim.x) {
        int i0 = b * 1024 + tid * 4;
        int s = 0;
        #pragma unroll
        for (int j = 0; j < 4; ++j) { int i = i0 + j; if (i < N) s += cnt[i]; }
        #pragma unroll
        for (int d = 1; d < 64; d <<= 1) s += __shfl_xor(s, d, 64);
        if ((tid & 63) == 0) wsh[tid >> 6] = s;
        __syncthreads();
        if (tid == 0) bsum[b] = wsh[0] + wsh[1] + wsh[2] + wsh[3];
        __syncthreads();
    }
    g.sync();

    // P3: full scan -> off, cursor
    for (int b = blockIdx.x; b < NB; b += gridDim.x) {
        int lane = tid & 63, wv = tid >> 6;
        int bp = 0;
        for (int j = 0; j < b; ++j) bp += bsum[j];   // uniform scalar loop (NB<=64)
        int i0 = b * 1024 + tid * 4;
        int v[4]; int s = 0;
        #pragma unroll
        for (int j = 0; j < 4; ++j) { int i = i0 + j; v[j] = (i < N) ? cnt[i] : 0; s += v[j]; }
        int sc = s;
        #pragma unroll
        for (int d = 1; d < 64; d <<= 1) { int u = __shfl_up(sc, d, 64); if (lane >= d) sc += u; }
        if (lane == 63) wsh[wv] = sc;
        __syncthreads();
        int wp = 0;
        for (int j = 0; j < wv; ++j) wp += wsh[j];
        int base = bp + wp + sc - s;
        #pragma unroll
        for (int j = 0; j < 4; ++j) {
            int i = i0 + j;
            if (i < N) { cursor[i] = base; off[i + 1] = base + v[j]; }
            base += v[j];
        }
        if (b == 0 && tid == 0) off[0] = 0;
        __syncthreads();
    }
    g.sync();

    // P4: CSR pair scatter
    for (int e = gtid; e < E; e += gsz) {
        int d2 = dst[e];
        int slot = atomicAdd(&cursor[d2], 1);
        pairs[slot] = (long long)(unsigned)src[e] | ((long long)e << 32);
    }
    g.sync();

    // P5: layer-1 aggregate (x -> agg)
    agg_phase(xb, ea, off, pairs, aggb, N);
    g.sync();

    // P6: layer-1 GEMM: z1 = relu(agg@W1l + b1l + x@W1r), bf16
    gemm_phase(aggb, xb, Wt1, b1l, nullptr, z1b, MT, N, 1, 1);
    g.sync();

    // P7: layer-2 aggregate (z1 -> agg)
    agg_phase(z1b, ea, off, pairs, aggb, N);
    g.sync();

    // P8: layer-2 GEMM: out = agg@W2l + b2l + z1@W2r, f32
    gemm_phase(aggb, z1b, Wt2, b2l, out, nullptr, MT, N, 0, 0);
}

extern "C" void kernel_launch(void* const* d_in, const int* in_sizes, int n_in,
                              void* d_out, int out_size, void* d_ws, size_t ws_size,
                              hipStream_t stream) {
    const float* x   = (const float*)d_in[0];
    const int*   ei  = (const int*)d_in[1];
    const float* ea  = (const float*)d_in[2];
    const float* W1l = (const float*)d_in[3];
    const float* b1l = (const float*)d_in[4];
    const float* W1r = (const float*)d_in[5];
    const float* W2l = (const float*)d_in[6];
    const float* b2l = (const float*)d_in[7];
    const float* W2r = (const float*)d_in[8];
    float* out = (float*)d_out;

    const int N = in_sizes[0] / D;   // 50000
    const int E = in_sizes[1] / 2;   // 1,600,000
    const int NP = (N + 31) & ~31;   // padded rows for 32-row GEMM tiles
    const int* src = ei;
    const int* dst = ei + E;

    char* ws = (char*)d_ws;
    size_t o = 0;
    auto alloc = [&](size_t bytes) -> void* {
        void* p = ws + o;
        o = (o + bytes + 255) & ~(size_t)255;
        return p;
    };
    int*   cnt    = (int*)alloc((size_t)N * 4);
    int*   off    = (int*)alloc((size_t)(N + 1) * 4);
    int*   cursor = (int*)alloc((size_t)N * 4);
    int*   bsum   = (int*)alloc(256 * 4);
    long long* pairs = (long long*)alloc((size_t)E * 8);
    unsigned short* xb   = (unsigned short*)alloc((size_t)NP * D * 2);
    unsigned short* z1b  = (unsigned short*)alloc((size_t)NP * D * 2);
    unsigned short* aggb = (unsigned short*)alloc((size_t)NP * D * 2);
    unsigned short* Wt1  = (unsigned short*)alloc(128 * 256 * 2);
    unsigned short* Wt2  = (unsigned short*)alloc(128 * 256 * 2);
    (void)ws_size; (void)n_in; (void)out_size;

    int NB = (N + 1023) / 1024;   // 49 (<= 64)
    int MT = (N + 31) / 32;       // 1563

    (void)hipMemsetAsync(cnt, 0, (size_t)N * 4, stream);

    int maxB = 0;
    (void)hipOccupancyMaxActiveBlocksPerMultiprocessor(&maxB, mega_kernel, 256, 0);
    if (maxB < 1) maxB = 1;
    if (maxB > 4) maxB = 4;
    int GB = maxB * 256;          // <= 1024 blocks, guaranteed co-resident

    void* args[] = {
        (void*)&x, (void*)&src, (void*)&dst, (void*)&ea,
        (void*)&W1l, (void*)&b1l, (void*)&W1r,
        (void*)&W2l, (void*)&b2l, (void*)&W2r,
        (void*)&cnt, (void*)&bsum, (void*)&off, (void*)&cursor, (void*)&pairs,
        (void*)&xb, (void*)&z1b, (void*)&aggb, (void*)&Wt1, (void*)&Wt2,
        (void*)&out, (void*)&N, (void*)&E, (void*)&NB, (void*)&MT
    };
    (void)hipLaunchCooperativeKernel(mega_kernel, dim3(GB), dim3(256), args, 0, stream);
}

// Round 13
// 814.186 us; speedup vs baseline: 1.2827x; 1.2827x over previous
//
#include <hip/hip_runtime.h>

#define D 128

typedef __attribute__((ext_vector_type(8))) short bf16x8;          // 8 bf16 (4 VGPRs)
typedef __attribute__((ext_vector_type(4))) float f32x4;           // MFMA accum / NT loads
typedef __attribute__((ext_vector_type(4))) unsigned short u16x4;  // 4 bf16
typedef __attribute__((ext_vector_type(4))) unsigned char u8x4;    // 4 fp8

__device__ inline unsigned short f2bf(float f) {
    union { float f; unsigned u; } v; v.f = f;
    unsigned r = v.u + 0x7FFF + ((v.u >> 16) & 1);   // RNE
    return (unsigned short)(r >> 16);
}
__device__ inline float bf2f(unsigned short h) {
    union { unsigned u; float f; } v; v.u = ((unsigned)h) << 16; return v.f;
}
// fp8 e4m3fn encode (RNE, flush-to-zero below 2^-6; |f| < 448 assumed)
__device__ inline unsigned char f2fp8(float f) {
    unsigned u = __float_as_uint(f);
    unsigned s = (u >> 31) << 7;
    unsigned r = (u & 0x7fffffffu) + 0x7FFFF + ((u >> 20) & 1);
    int e = (int)(r >> 23) - 127;
    if (e < -6) return (unsigned char)s;
    return (unsigned char)(s | ((unsigned)(e + 7) << 3) | ((r >> 20) & 7));
}
__device__ inline float fp82f(unsigned c) {
    unsigned ef = (c >> 3) & 0xF, m = c & 7, s = c >> 7;
    unsigned nb = (s << 31) | ((ef + 120) << 23) | (m << 20);
    float nv = __uint_as_float(nb);
    float sv = (s ? -0.001953125f : 0.001953125f) * (float)m;  // subnormal: m * 2^-9
    return ef ? nv : sv;
}

// ---- prep: x->bf16 | dst count | W transpose ----

__global__ __launch_bounds__(256) void prep_kernel(const float* __restrict__ x,
                                                   unsigned short* __restrict__ xb, int n4,
                                                   const int* __restrict__ dst,
                                                   int* __restrict__ cnt, int E,
                                                   const float* __restrict__ W1l,
                                                   const float* __restrict__ W1r,
                                                   const float* __restrict__ W2l,
                                                   const float* __restrict__ W2r,
                                                   unsigned short* __restrict__ Wt1,
                                                   unsigned short* __restrict__ Wt2,
                                                   int CAST_B, int CNT_B) {
    int b = blockIdx.x, tid = threadIdx.x;
    if (b < CAST_B) {
        int i = b * 256 + tid;
        if (i < n4) {
            float4 v = reinterpret_cast<const float4*>(x)[i];
            ushort4 r;
            r.x = f2bf(v.x); r.y = f2bf(v.y); r.z = f2bf(v.z); r.w = f2bf(v.w);
            reinterpret_cast<ushort4*>(xb)[i] = r;
        }
    } else if (b < CAST_B + CNT_B) {
        int e = (b - CAST_B) * 256 + tid;
        if (e < E) atomicAdd(&cnt[dst[e]], 1);
    } else {
        int c = b - CAST_B - CNT_B;   // 0..127
        int k = tid;                  // 0..255
        float v1 = (k < 128) ? W1l[k * 128 + c] : W1r[(k - 128) * 128 + c];
        float v2 = (k < 128) ? W2l[k * 128 + c] : W2r[(k - 128) * 128 + c];
        Wt1[c * 256 + k] = f2bf(v1);
        Wt2[c * 256 + k] = f2bf(v2);
    }
}

// ---------------- CSR scan ----------------

__global__ __launch_bounds__(256) void psum_kernel(const int* __restrict__ cnt,
                                                   int* __restrict__ bsum, int n) {
    __shared__ int wsh[4];
    int b = blockIdx.x, tid = threadIdx.x;
    int i0 = b * 1024 + tid * 4;
    int s = 0;
    #pragma unroll
    for (int j = 0; j < 4; ++j) { int i = i0 + j; if (i < n) s += cnt[i]; }
    #pragma unroll
    for (int d = 1; d < 64; d <<= 1) s += __shfl_xor(s, d, 64);
    if ((tid & 63) == 0) wsh[tid >> 6] = s;
    __syncthreads();
    if (tid == 0) bsum[b] = wsh[0] + wsh[1] + wsh[2] + wsh[3];
}

__global__ __launch_bounds__(256) void fscan_kernel(const int* __restrict__ cnt,
                                                    const int* __restrict__ bsum,
                                                    int* __restrict__ off,
                                                    int* __restrict__ cursor, int n) {
    __shared__ int wsum[4];
    int b = blockIdx.x, tid = threadIdx.x;
    int lane = tid & 63, wv = tid >> 6;
    int bp = 0;
    for (int j = 0; j < b; ++j) bp += bsum[j];   // uniform scalar loop (NB<=64)
    int i0 = b * 1024 + tid * 4;
    int v[4]; int s = 0;
    #pragma unroll
    for (int j = 0; j < 4; ++j) { int i = i0 + j; v[j] = (i < n) ? cnt[i] : 0; s += v[j]; }
    int sc = s;
    #pragma unroll
    for (int d = 1; d < 64; d <<= 1) { int u = __shfl_up(sc, d, 64); if (lane >= d) sc += u; }
    if (lane == 63) wsum[wv] = sc;
    __syncthreads();
    int wp = 0;
    for (int j = 0; j < wv; ++j) wp += wsum[j];
    int base = bp + wp + sc - s;
    #pragma unroll
    for (int j = 0; j < 4; ++j) {
        int i = i0 + j;
        if (i < n) { cursor[i] = base; off[i + 1] = base + v[j]; }
        base += v[j];
    }
    if (b == 0 && tid == 0) off[0] = 0;
}

// ---- fill: CSR scatter of (src,dst) pairs + fp8 ea copy in CSR order ----
// Wave = 2 adjacent edges (sequential 1 KB ea read); half-wave per edge.
// Exec-uniform shfl: slot atomic by lanes 0/32 (guard has no shfl), then broadcast.

__global__ __launch_bounds__(256) void fill_kernel(const int* __restrict__ src,
                                                   const int* __restrict__ dst,
                                                   int* __restrict__ cursor,
                                                   long long* __restrict__ pairs,
                                                   const float* __restrict__ ea,
                                                   unsigned char* __restrict__ eaq, int E) {
    int gw = (blockIdx.x * 256 + threadIdx.x) >> 6;   // global wave id
    int nw = (gridDim.x * 256) >> 6;
    int t = threadIdx.x & 63;
    int hf = t >> 5, l32 = t & 31;
    for (int e0 = gw * 2; e0 < E; e0 += nw * 2) {     // E even
        int e = e0 + hf;
        int d2 = dst[e];
        int slot = 0;
        if (l32 == 0) slot = atomicAdd(&cursor[d2], 1);   // no shfl inside guard
        slot = __shfl(slot, hf << 5, 64);                 // all 64 lanes active
        f32x4 ev = __builtin_nontemporal_load(
            reinterpret_cast<const f32x4*>(&ea[(size_t)e * D + l32 * 4]));
        u8x4 q;
        q[0] = f2fp8(ev[0]); q[1] = f2fp8(ev[1]);
        q[2] = f2fp8(ev[2]); q[3] = f2fp8(ev[3]);
        *reinterpret_cast<u8x4*>(&eaq[(size_t)slot * D + l32 * 4]) = q;  // plain: L3-resident
        if (l32 == 0) pairs[slot] = (long long)(unsigned)src[e] | ((long long)d2 << 32);
    }
}

// ---- aggregate: edge-parallel segmented sum of relu(feat[src] + eaq[slot]) ----
// Half-wave owns 32 contiguous CSR slots (E % 32 == 0). 4-slot batches: broadcast
// pair loads + sequential eaq + gathered feat issued together; running sum flushed
// at segment boundaries via atomicAdd into zeroed f32 agg. No shfl anywhere.

__global__ __launch_bounds__(256) void aggregate_kernel(const unsigned short* __restrict__ featb,
                                                        const unsigned char* __restrict__ eaq,
                                                        const long long* __restrict__ pairs,
                                                        float* __restrict__ aggf, int E) {
    int hw = (blockIdx.x * 256 + threadIdx.x) >> 5;   // global half-wave id
    int l32 = threadIdx.x & 31;
    int s0 = hw * 32;
    if (s0 >= E) return;

    float a0 = 0.f, a1 = 0.f, a2 = 0.f, a3 = 0.f;
    int cur = -1;

    auto flush = [&]() {
        float* p = &aggf[(size_t)cur * D + l32 * 4];
        atomicAdd(p + 0, a0);
        atomicAdd(p + 1, a1);
        atomicAdd(p + 2, a2);
        atomicAdd(p + 3, a3);
        a0 = a1 = a2 = a3 = 0.f;
    };

    #pragma unroll 2
    for (int j = 0; j < 8; ++j) {
        int sb = s0 + j * 4;
        // issue all loads for the 4-slot batch up front
        long long p0 = pairs[sb + 0];
        long long p1 = pairs[sb + 1];
        long long p2 = pairs[sb + 2];
        long long p3 = pairs[sb + 3];
        u8x4 q0 = *reinterpret_cast<const u8x4*>(&eaq[(size_t)(sb + 0) * D + l32 * 4]);
        u8x4 q1 = *reinterpret_cast<const u8x4*>(&eaq[(size_t)(sb + 1) * D + l32 * 4]);
        u8x4 q2 = *reinterpret_cast<const u8x4*>(&eaq[(size_t)(sb + 2) * D + l32 * 4]);
        u8x4 q3 = *reinterpret_cast<const u8x4*>(&eaq[(size_t)(sb + 3) * D + l32 * 4]);
        u16x4 x0 = *reinterpret_cast<const u16x4*>(&featb[(size_t)(int)p0 * D + l32 * 4]);
        u16x4 x1 = *reinterpret_cast<const u16x4*>(&featb[(size_t)(int)p1 * D + l32 * 4]);
        u16x4 x2 = *reinterpret_cast<const u16x4*>(&featb[(size_t)(int)p2 * D + l32 * 4]);
        u16x4 x3 = *reinterpret_cast<const u16x4*>(&featb[(size_t)(int)p3 * D + l32 * 4]);

        int d0 = (int)(p0 >> 32), d1 = (int)(p1 >> 32);
        int d2 = (int)(p2 >> 32), d3 = (int)(p3 >> 32);

        if (d0 != cur) { if (cur >= 0) flush(); cur = d0; }
        a0 += fmaxf(bf2f(x0[0]) + fp82f(q0[0]), 0.f);
        a1 += fmaxf(bf2f(x0[1]) + fp82f(q0[1]), 0.f);
        a2 += fmaxf(bf2f(x0[2]) + fp82f(q0[2]), 0.f);
        a3 += fmaxf(bf2f(x0[3]) + fp82f(q0[3]), 0.f);
        if (d1 != cur) { flush(); cur = d1; }
        a0 += fmaxf(bf2f(x1[0]) + fp82f(q1[0]), 0.f);
        a1 += fmaxf(bf2f(x1[1]) + fp82f(q1[1]), 0.f);
        a2 += fmaxf(bf2f(x1[2]) + fp82f(q1[2]), 0.f);
        a3 += fmaxf(bf2f(x1[3]) + fp82f(q1[3]), 0.f);
        if (d2 != cur) { flush(); cur = d2; }
        a0 += fmaxf(bf2f(x2[0]) + fp82f(q2[0]), 0.f);
        a1 += fmaxf(bf2f(x2[1]) + fp82f(q2[1]), 0.f);
        a2 += fmaxf(bf2f(x2[2]) + fp82f(q2[2]), 0.f);
        a3 += fmaxf(bf2f(x2[3]) + fp82f(q2[3]), 0.f);
        if (d3 != cur) { flush(); cur = d3; }
        a0 += fmaxf(bf2f(x3[0]) + fp82f(q3[0]), 0.f);
        a1 += fmaxf(bf2f(x3[1]) + fp82f(q3[1]), 0.f);
        a2 += fmaxf(bf2f(x3[2]) + fp82f(q3[2]), 0.f);
        a3 += fmaxf(bf2f(x3[3]) + fp82f(q3[3]), 0.f);
    }
    flush();   // cur >= 0 (window non-empty)
}

// ---- MFMA GEMM: out = act(scale(A1)@W1part + A2@W2part + bias) ----
// A1 = f32 agg with per-row inv-degree scaling (mean fused here); A2 = bf16 feat.
// 4 waves/block; wave w owns cols [32w,32w+32); B-frags persist in registers.

template <int RELU, int OUT_BF16>
__global__ __launch_bounds__(256) void gemm_mfma_kernel(const float* __restrict__ A1f,
                                                        const unsigned short* __restrict__ A2,
                                                        const int* __restrict__ off,
                                                        const unsigned short* __restrict__ Wt,
                                                        const float* __restrict__ bias,
                                                        float* __restrict__ outf,
                                                        unsigned short* __restrict__ outb,
                                                        int MT, int N) {
    int tid = threadIdx.x;
    int w = tid >> 6;
    int l = tid & 63;
    int lr = l & 15;
    int lg = l >> 4;
    int c0 = w * 32;

    bf16x8 bfr[2][8];
    #pragma unroll
    for (int t = 0; t < 2; ++t)
        #pragma unroll
        for (int kc = 0; kc < 8; ++kc)
            bfr[t][kc] = *reinterpret_cast<const bf16x8*>(
                &Wt[(size_t)(c0 + t * 16 + lr) * 256 + kc * 32 + lg * 8]);

    for (int mt = blockIdx.x; mt < MT; mt += gridDim.x) {
        int r0 = mt * 32;
        int rowA = r0 + lr, rowB = r0 + 16 + lr;
        float invA = 1.f, invB = 1.f;
        if (rowA < N) { int dg = off[rowA + 1] - off[rowA]; invA = 1.f / (float)(dg > 0 ? dg : 1); }
        if (rowB < N) { int dg = off[rowB + 1] - off[rowB]; invB = 1.f / (float)(dg > 0 ? dg : 1); }

        f32x4 acc[2][2];
        #pragma unroll
        for (int tr = 0; tr < 2; ++tr)
            #pragma unroll
            for (int tc = 0; tc < 2; ++tc) acc[tr][tc] = {0.f, 0.f, 0.f, 0.f};

        #pragma unroll
        for (int kc = 0; kc < 8; ++kc) {
            int k = (kc & 3) * 32 + lg * 8;
            bf16x8 af0, af1;
            if (kc < 4) {
                f32x4 u0 = *reinterpret_cast<const f32x4*>(&A1f[(size_t)rowA * D + k]);
                f32x4 u1 = *reinterpret_cast<const f32x4*>(&A1f[(size_t)rowA * D + k + 4]);
                f32x4 v0 = *reinterpret_cast<const f32x4*>(&A1f[(size_t)rowB * D + k]);
                f32x4 v1 = *reinterpret_cast<const f32x4*>(&A1f[(size_t)rowB * D + k + 4]);
                #pragma unroll
                for (int i = 0; i < 4; ++i) {
                    af0[i]     = (short)f2bf(u0[i] * invA);
                    af0[i + 4] = (short)f2bf(u1[i] * invA);
                    af1[i]     = (short)f2bf(v0[i] * invB);
                    af1[i + 4] = (short)f2bf(v1[i] * invB);
                }
            } else {
                af0 = *reinterpret_cast<const bf16x8*>(&A2[(size_t)rowA * D + k]);
                af1 = *reinterpret_cast<const bf16x8*>(&A2[(size_t)rowB * D + k]);
            }
            acc[0][0] = __builtin_amdgcn_mfma_f32_16x16x32_bf16(af0, bfr[0][kc], acc[0][0], 0, 0, 0);
            acc[1][0] = __builtin_amdgcn_mfma_f32_16x16x32_bf16(af1, bfr[0][kc], acc[1][0], 0, 0, 0);
            acc[0][1] = __builtin_amdgcn_mfma_f32_16x16x32_bf16(af0, bfr[1][kc], acc[0][1], 0, 0, 0);
            acc[1][1] = __builtin_amdgcn_mfma_f32_16x16x32_bf16(af1, bfr[1][kc], acc[1][1], 0, 0, 0);
        }

        #pragma unroll
        for (int tc = 0; tc < 2; ++tc) {
            int col = c0 + tc * 16 + lr;
            float bv = bias[col];
            #pragma unroll
            for (int tr = 0; tr < 2; ++tr) {
                #pragma unroll
                for (int r = 0; r < 4; ++r) {
                    int row = r0 + tr * 16 + lg * 4 + r;
                    if (row < N) {
                        float v = acc[tr][tc][r] + bv;
                        if (RELU) v = fmaxf(v, 0.f);
                        if (OUT_BF16) outb[(size_t)row * D + col] = f2bf(v);
                        else outf[(size_t)row * D + col] = v;
                    }
                }
            }
        }
    }
}

extern "C" void kernel_launch(void* const* d_in, const int* in_sizes, int n_in,
                              void* d_out, int out_size, void* d_ws, size_t ws_size,
                              hipStream_t stream) {
    const float* x   = (const float*)d_in[0];
    const int*   ei  = (const int*)d_in[1];
    const float* ea  = (const float*)d_in[2];
    const float* W1l = (const float*)d_in[3];
    const float* b1l = (const float*)d_in[4];
    const float* W1r = (const float*)d_in[5];
    const float* W2l = (const float*)d_in[6];
    const float* b2l = (const float*)d_in[7];
    const float* W2r = (const float*)d_in[8];
    float* out = (float*)d_out;

    const int N = in_sizes[0] / D;   // 50000
    const int E = in_sizes[1] / 2;   // 1,600,000 (divisible by 32)
    const int NP = (N + 31) & ~31;
    const int* src = ei;
    const int* dst = ei + E;

    char* ws = (char*)d_ws;
    size_t o = 0;
    auto alloc = [&](size_t bytes) -> void* {
        void* p = ws + o;
        o = (o + bytes + 255) & ~(size_t)255;
        return p;
    };
    int*   cnt    = (int*)alloc((size_t)N * 4);
    int*   off    = (int*)alloc((size_t)(N + 1) * 4);
    int*   cursor = (int*)alloc((size_t)N * 4);
    int*   bsum   = (int*)alloc(256 * 4);
    long long* pairs = (long long*)alloc((size_t)E * 8);
    unsigned char* eaq = (unsigned char*)alloc((size_t)E * D);      // 205 MB fp8, CSR order
    float* aggf1 = (float*)alloc((size_t)NP * D * 4);               // 25.6 MB f32
    float* aggf2 = (float*)alloc((size_t)NP * D * 4);
    unsigned short* xb  = (unsigned short*)alloc((size_t)NP * D * 2);
    unsigned short* z1b = (unsigned short*)alloc((size_t)NP * D * 2);
    unsigned short* Wt1 = (unsigned short*)alloc(128 * 256 * 2);
    unsigned short* Wt2 = (unsigned short*)alloc(128 * 256 * 2);
    (void)ws_size; (void)n_in; (void)out_size;

    const int MT = (N + 31) / 32;
    const int NB = (N + 1023) / 1024;   // 49 (<= 64)
    const int n4 = N * D / 4;
    const int CAST_B = (n4 + 255) / 256;
    const int CNT_B = (E + 255) / 256;
    const int AGB = (E / 32 + 7) / 8;   // 8 half-waves (256 thr) per block

    (void)hipMemsetAsync(cnt, 0, (size_t)N * 4, stream);
    (void)hipMemsetAsync(aggf1, 0, (size_t)NP * D * 4, stream);
    (void)hipMemsetAsync(aggf2, 0, (size_t)NP * D * 4, stream);

    prep_kernel<<<CAST_B + CNT_B + 128, 256, 0, stream>>>(x, xb, n4, dst, cnt, E,
                                                          W1l, W1r, W2l, W2r, Wt1, Wt2,
                                                          CAST_B, CNT_B);
    psum_kernel<<<NB, 256, 0, stream>>>(cnt, bsum, N);
    fscan_kernel<<<NB, 256, 0, stream>>>(cnt, bsum, off, cursor, N);
    fill_kernel<<<4096, 256, 0, stream>>>(src, dst, cursor, pairs, ea, eaq, E);

    // Layer 1
    aggregate_kernel<<<AGB, 256, 0, stream>>>(xb, eaq, pairs, aggf1, E);
    gemm_mfma_kernel<1, 1><<<1024, 256, 0, stream>>>(aggf1, xb, off, Wt1, b1l,
                                                     nullptr, z1b, MT, N);
    // Layer 2
    aggregate_kernel<<<AGB, 256, 0, stream>>>(z1b, eaq, pairs, aggf2, E);
    gemm_mfma_kernel<0, 0><<<1024, 256, 0, stream>>>(aggf2, z1b, off, Wt2, b2l,
                                                     out, nullptr, MT, N);
}

// Round 14
// 650.503 us; speedup vs baseline: 1.6055x; 1.2516x over previous
//
#include <hip/hip_runtime.h>

#define D 128

typedef __attribute__((ext_vector_type(8))) short bf16x8;          // 8 bf16 (4 VGPRs)
typedef __attribute__((ext_vector_type(4))) float f32x4;           // MFMA accum / NT loads
typedef __attribute__((ext_vector_type(4))) unsigned short u16x4;  // 4 bf16
typedef __attribute__((ext_vector_type(8))) unsigned short u16x8;  // 8 bf16
typedef __attribute__((ext_vector_type(4))) unsigned char u8x4;    // 4 fp8
typedef __attribute__((ext_vector_type(8))) unsigned char u8x8;    // 8 fp8

__device__ inline unsigned short f2bf(float f) {
    union { float f; unsigned u; } v; v.f = f;
    unsigned r = v.u + 0x7FFF + ((v.u >> 16) & 1);   // RNE
    return (unsigned short)(r >> 16);
}
__device__ inline float bf2f(unsigned short h) {
    union { unsigned u; float f; } v; v.u = ((unsigned)h) << 16; return v.f;
}
// fp8 e4m3 encode (RNE, flush-to-zero below 2^-6; |f| < 448 assumed).
// Never emits subnormals: output is either 0 or a normal with exp>=1.
__device__ inline unsigned char f2fp8(float f) {
    unsigned u = __float_as_uint(f);
    unsigned s = (u >> 31) << 7;
    unsigned r = (u & 0x7fffffffu) + 0x7FFFF + ((u >> 20) & 1);
    int e = (int)(r >> 23) - 127;
    if (e < -6) return (unsigned char)s;
    return (unsigned char)(s | ((unsigned)(e + 7) << 3) | ((r >> 20) & 7));
}
// Exact inverse of f2fp8 (encoder never emits subnormals -> mag<8 means true zero).
__device__ inline float fp8d(unsigned c) {
    unsigned mag = c & 0x7f;
    unsigned bf = (mag << 4) + 0x3C00 + ((c >> 7) << 15);  // bf16 bits (no carry into sign)
    union { unsigned u; float f; } v; v.u = bf << 16;
    return (mag >> 3) ? v.f : 0.f;
}

// ---- prep: x->bf16+fp8 | dst count | W transpose ----

__global__ __launch_bounds__(256) void prep_kernel(const float* __restrict__ x,
                                                   unsigned short* __restrict__ xb,
                                                   unsigned char* __restrict__ xq, int n4,
                                                   const int* __restrict__ dst,
                                                   int* __restrict__ cnt, int E,
                                                   const float* __restrict__ W1l,
                                                   const float* __restrict__ W1r,
                                                   const float* __restrict__ W2l,
                                                   const float* __restrict__ W2r,
                                                   unsigned short* __restrict__ Wt1,
                                                   unsigned short* __restrict__ Wt2,
                                                   int CAST_B, int CNT_B) {
    int b = blockIdx.x, tid = threadIdx.x;
    if (b < CAST_B) {
        int i = b * 256 + tid;
        if (i < n4) {
            float4 v = reinterpret_cast<const float4*>(x)[i];
            ushort4 r;
            r.x = f2bf(v.x); r.y = f2bf(v.y); r.z = f2bf(v.z); r.w = f2bf(v.w);
            reinterpret_cast<ushort4*>(xb)[i] = r;
            u8x4 q;
            q[0] = f2fp8(v.x); q[1] = f2fp8(v.y); q[2] = f2fp8(v.z); q[3] = f2fp8(v.w);
            reinterpret_cast<u8x4*>(xq)[i] = q;
        }
    } else if (b < CAST_B + CNT_B) {
        int e = (b - CAST_B) * 256 + tid;
        if (e < E) atomicAdd(&cnt[dst[e]], 1);
    } else {
        int c = b - CAST_B - CNT_B;   // 0..127
        int k = tid;                  // 0..255
        float v1 = (k < 128) ? W1l[k * 128 + c] : W1r[(k - 128) * 128 + c];
        float v2 = (k < 128) ? W2l[k * 128 + c] : W2r[(k - 128) * 128 + c];
        Wt1[c * 256 + k] = f2bf(v1);
        Wt2[c * 256 + k] = f2bf(v2);
    }
}

// ---------------- CSR scan ----------------

__global__ __launch_bounds__(256) void psum_kernel(const int* __restrict__ cnt,
                                                   int* __restrict__ bsum, int n) {
    __shared__ int wsh[4];
    int b = blockIdx.x, tid = threadIdx.x;
    int i0 = b * 1024 + tid * 4;
    int s = 0;
    #pragma unroll
    for (int j = 0; j < 4; ++j) { int i = i0 + j; if (i < n) s += cnt[i]; }
    #pragma unroll
    for (int d = 1; d < 64; d <<= 1) s += __shfl_xor(s, d, 64);
    if ((tid & 63) == 0) wsh[tid >> 6] = s;
    __syncthreads();
    if (tid == 0) bsum[b] = wsh[0] + wsh[1] + wsh[2] + wsh[3];
}

__global__ __launch_bounds__(256) void fscan_kernel(const int* __restrict__ cnt,
                                                    const int* __restrict__ bsum,
                                                    int* __restrict__ off,
                                                    int* __restrict__ cursor, int n) {
    __shared__ int wsum[4];
    int b = blockIdx.x, tid = threadIdx.x;
    int lane = tid & 63, wv = tid >> 6;
    int bp = 0;
    for (int j = 0; j < b; ++j) bp += bsum[j];   // uniform scalar loop (NB<=64)
    int i0 = b * 1024 + tid * 4;
    int v[4]; int s = 0;
    #pragma unroll
    for (int j = 0; j < 4; ++j) { int i = i0 + j; v[j] = (i < n) ? cnt[i] : 0; s += v[j]; }
    int sc = s;
    #pragma unroll
    for (int d = 1; d < 64; d <<= 1) { int u = __shfl_up(sc, d, 64); if (lane >= d) sc += u; }
    if (lane == 63) wsum[wv] = sc;
    __syncthreads();
    int wp = 0;
    for (int j = 0; j < wv; ++j) wp += wsum[j];
    int base = bp + wp + sc - s;
    #pragma unroll
    for (int j = 0; j < 4; ++j) {
        int i = i0 + j;
        if (i < n) { cursor[i] = base; off[i + 1] = base + v[j]; }
        base += v[j];
    }
    if (b == 0 && tid == 0) off[0] = 0;
}

// ---- fill: CSR slot scatter + fp8 ea copy in CSR order (proven R10 shape) ----
// Wave = 2 adjacent edges (sequential 1 KB ea read); half-wave per edge.
// Exec-uniform shfl: slot atomic by lanes 0/32 (guard has no shfl), then broadcast.

__global__ __launch_bounds__(256) void fill_kernel(const int* __restrict__ src,
                                                   const int* __restrict__ dst,
                                                   int* __restrict__ cursor,
                                                   int* __restrict__ pairsrc,
                                                   const float* __restrict__ ea,
                                                   unsigned char* __restrict__ eaq, int E) {
    int gw = (blockIdx.x * 256 + threadIdx.x) >> 6;   // global wave id
    int nw = (gridDim.x * 256) >> 6;
    int t = threadIdx.x & 63;
    int hf = t >> 5, l32 = t & 31;
    for (int e0 = gw * 2; e0 < E; e0 += nw * 2) {     // E even
        int e = e0 + hf;
        int slot = 0;
        if (l32 == 0) slot = atomicAdd(&cursor[dst[e]], 1);   // no shfl inside guard
        slot = __shfl(slot, hf << 5, 64);                     // all 64 lanes active
        f32x4 ev = __builtin_nontemporal_load(
            reinterpret_cast<const f32x4*>(&ea[(size_t)e * D + l32 * 4]));
        u8x4 q;
        q[0] = f2fp8(ev[0]); q[1] = f2fp8(ev[1]);
        q[2] = f2fp8(ev[2]); q[3] = f2fp8(ev[3]);
        *reinterpret_cast<u8x4*>(&eaq[(size_t)slot * D + l32 * 4]) = q;
        if (l32 == 0) pairsrc[slot] = src[e];
    }
}

// ---- aggregate: agg = mean_dst relu(featq[src] + eaq[slot]), all-fp8 gather ----
// 4 waves/block, 1 node/wave, QUARTER-wave (16 lanes) per edge, u8x8 loads:
// feat row = 128 B = 2 lines (table 6.4 MB, mostly L2-resident), eaq sequential.
// 8 edges in flight per wave. All shfl sites exec-uniform; tails guard accum only.

__global__ __launch_bounds__(256) void aggregate_kernel(const unsigned char* __restrict__ featq,
                                                        const unsigned char* __restrict__ eaq,
                                                        const int* __restrict__ off,
                                                        const int* __restrict__ pairsrc,
                                                        unsigned short* __restrict__ aggb,
                                                        int N) {
    int nd = blockIdx.x * 4 + (threadIdx.x >> 6);
    if (nd >= N) return;
    int t = threadIdx.x & 63;
    int qt = t >> 4, l16 = t & 15;
    int s = off[nd], e = off[nd + 1];
    float a[8];
    #pragma unroll
    for (int j = 0; j < 8; ++j) a[j] = 0.f;

    for (int b = s; b < e; b += 64) {
        int cnt = min(64, e - b);
        int psrc = (b + t < e) ? pairsrc[b + t] : 0;

        auto fetch = [&](int idx, u8x8& ev, u8x8& xv) {
            int sidx = __shfl(psrc, idx, 64);
            ev = *reinterpret_cast<const u8x8*>(&eaq[(size_t)(b + idx) * D + l16 * 8]);
            xv = *reinterpret_cast<const u8x8*>(&featq[(size_t)sidx * D + l16 * 8]);
        };
        auto accum = [&](const u8x8& ev, const u8x8& xv) {
            #pragma unroll
            for (int j = 0; j < 8; ++j)
                a[j] += fmaxf(fp8d(xv[j]) + fp8d(ev[j]), 0.f);
        };

        int p = 0;
        for (; p + 8 <= cnt; p += 8) {          // uniform condition
            u8x8 e0, x0, e1, x1;
            fetch(p + qt, e0, x0);
            fetch(p + 4 + qt, e1, x1);
            accum(e0, x0); accum(e1, x1);
        }
        if (p + 4 <= cnt) {                     // uniform
            u8x8 e0, x0;
            fetch(p + qt, e0, x0);
            accum(e0, x0);
            p += 4;
        }
        if (p < cnt) {                          // uniform; 1..3 edges left
            int rem = cnt - p;
            int idx = p + (qt < rem ? qt : 0);  // per-lane idx; all lanes execute
            u8x8 e0, x0;
            fetch(idx, e0, x0);                 // shfl exec-uniform
            if (qt < rem) accum(e0, x0);        // guard: no shfl inside
        }
    }

    #pragma unroll
    for (int j = 0; j < 8; ++j) {
        a[j] += __shfl_xor(a[j], 16, 64);
        a[j] += __shfl_xor(a[j], 32, 64);
    }
    int deg = e - s;
    float inv = 1.f / (float)(deg > 0 ? deg : 1);
    if (qt == 0) {
        u16x8 r;
        #pragma unroll
        for (int j = 0; j < 8; ++j) r[j] = f2bf(a[j] * inv);
        *reinterpret_cast<u16x8*>(&aggb[(size_t)nd * D + l16 * 8]) = r;
    }
}

// ---- MFMA GEMM: out = act([A1|A2](Nx256) @ Wt^T + bias); optional fp8 copy ----

template <int RELU, int OUT_BF16>
__global__ __launch_bounds__(256) void gemm_mfma_kernel(const unsigned short* __restrict__ A1,
                                                        const unsigned short* __restrict__ A2,
                                                        const unsigned short* __restrict__ Wt,
                                                        const float* __restrict__ bias,
                                                        float* __restrict__ outf,
                                                        unsigned short* __restrict__ outb,
                                                        unsigned char* __restrict__ outq,
                                                        int MT, int N) {
    int tid = threadIdx.x;
    int w = tid >> 6;
    int l = tid & 63;
    int lr = l & 15;
    int lg = l >> 4;
    int c0 = w * 32;

    bf16x8 bfr[2][8];
    #pragma unroll
    for (int t = 0; t < 2; ++t)
        #pragma unroll
        for (int kc = 0; kc < 8; ++kc)
            bfr[t][kc] = *reinterpret_cast<const bf16x8*>(
                &Wt[(size_t)(c0 + t * 16 + lr) * 256 + kc * 32 + lg * 8]);

    for (int mt = blockIdx.x; mt < MT; mt += gridDim.x) {
        int r0 = mt * 32;
        f32x4 acc[2][2];
        #pragma unroll
        for (int tr = 0; tr < 2; ++tr)
            #pragma unroll
            for (int tc = 0; tc < 2; ++tc) acc[tr][tc] = {0.f, 0.f, 0.f, 0.f};

        #pragma unroll
        for (int kc = 0; kc < 8; ++kc) {
            const unsigned short* Ap = (kc < 4) ? A1 : A2;
            int k = (kc & 3) * 32 + lg * 8;
            bf16x8 af0 = *reinterpret_cast<const bf16x8*>(&Ap[(size_t)(r0 + lr) * D + k]);
            bf16x8 af1 = *reinterpret_cast<const bf16x8*>(&Ap[(size_t)(r0 + 16 + lr) * D + k]);
            acc[0][0] = __builtin_amdgcn_mfma_f32_16x16x32_bf16(af0, bfr[0][kc], acc[0][0], 0, 0, 0);
            acc[1][0] = __builtin_amdgcn_mfma_f32_16x16x32_bf16(af1, bfr[0][kc], acc[1][0], 0, 0, 0);
            acc[0][1] = __builtin_amdgcn_mfma_f32_16x16x32_bf16(af0, bfr[1][kc], acc[0][1], 0, 0, 0);
            acc[1][1] = __builtin_amdgcn_mfma_f32_16x16x32_bf16(af1, bfr[1][kc], acc[1][1], 0, 0, 0);
        }

        #pragma unroll
        for (int tc = 0; tc < 2; ++tc) {
            int col = c0 + tc * 16 + lr;
            float bv = bias[col];
            #pragma unroll
            for (int tr = 0; tr < 2; ++tr) {
                #pragma unroll
                for (int r = 0; r < 4; ++r) {
                    int row = r0 + tr * 16 + lg * 4 + r;
                    if (row < N) {
                        float v = acc[tr][tc][r] + bv;
                        if (RELU) v = fmaxf(v, 0.f);
                        if (OUT_BF16) {
                            outb[(size_t)row * D + col] = f2bf(v);
                            outq[(size_t)row * D + col] = f2fp8(v);
                        } else {
                            outf[(size_t)row * D + col] = v;
                        }
                    }
                }
            }
        }
    }
}

extern "C" void kernel_launch(void* const* d_in, const int* in_sizes, int n_in,
                              void* d_out, int out_size, void* d_ws, size_t ws_size,
                              hipStream_t stream) {
    const float* x   = (const float*)d_in[0];
    const int*   ei  = (const int*)d_in[1];
    const float* ea  = (const float*)d_in[2];
    const float* W1l = (const float*)d_in[3];
    const float* b1l = (const float*)d_in[4];
    const float* W1r = (const float*)d_in[5];
    const float* W2l = (const float*)d_in[6];
    const float* b2l = (const float*)d_in[7];
    const float* W2r = (const float*)d_in[8];
    float* out = (float*)d_out;

    const int N = in_sizes[0] / D;   // 50000
    const int E = in_sizes[1] / 2;   // 1,600,000 (even)
    const int NP = (N + 31) & ~31;   // padded rows for 32-row GEMM tiles
    const int* src = ei;
    const int* dst = ei + E;

    char* ws = (char*)d_ws;
    size_t o = 0;
    auto alloc = [&](size_t bytes) -> void* {
        void* p = ws + o;
        o = (o + bytes + 255) & ~(size_t)255;
        return p;
    };
    int*   cnt     = (int*)alloc((size_t)N * 4);
    int*   off     = (int*)alloc((size_t)(N + 1) * 4);
    int*   cursor  = (int*)alloc((size_t)N * 4);
    int*   bsum    = (int*)alloc(256 * 4);
    int*   pairsrc = (int*)alloc((size_t)E * 4);
    unsigned char* eaq = (unsigned char*)alloc((size_t)E * D);   // 205 MB fp8, CSR order
    unsigned char* xq  = (unsigned char*)alloc((size_t)NP * D); // 6.4 MB fp8 gather table
    unsigned char* z1q = (unsigned char*)alloc((size_t)NP * D);
    unsigned short* xb   = (unsigned short*)alloc((size_t)NP * D * 2);
    unsigned short* z1b  = (unsigned short*)alloc((size_t)NP * D * 2);
    unsigned short* aggb = (unsigned short*)alloc((size_t)NP * D * 2);
    unsigned short* Wt1  = (unsigned short*)alloc(128 * 256 * 2);
    unsigned short* Wt2  = (unsigned short*)alloc(128 * 256 * 2);
    (void)ws_size; (void)n_in; (void)out_size;

    const int MT = (N + 31) / 32;      // 1563
    const int NB = (N + 1023) / 1024;  // 49 (<= 64)
    const int AGB = (N + 3) / 4;
    const int n4 = N * D / 4;
    const int CAST_B = (n4 + 255) / 256;
    const int CNT_B = (E + 255) / 256;

    (void)hipMemsetAsync(cnt, 0, (size_t)N * 4, stream);
    prep_kernel<<<CAST_B + CNT_B + 128, 256, 0, stream>>>(x, xb, xq, n4, dst, cnt, E,
                                                          W1l, W1r, W2l, W2r, Wt1, Wt2,
                                                          CAST_B, CNT_B);
    psum_kernel<<<NB, 256, 0, stream>>>(cnt, bsum, N);
    fscan_kernel<<<NB, 256, 0, stream>>>(cnt, bsum, off, cursor, N);
    fill_kernel<<<4096, 256, 0, stream>>>(src, dst, cursor, pairsrc, ea, eaq, E);

    // Layer 1: agg = mean relu(xq[src]+eaq); z1 = relu(agg@W1l + b1l + x@W1r) -> bf16+fp8
    aggregate_kernel<<<AGB, 256, 0, stream>>>(xq, eaq, off, pairsrc, aggb, N);
    gemm_mfma_kernel<1, 1><<<1024, 256, 0, stream>>>(aggb, xb, Wt1, b1l,
                                                     nullptr, z1b, z1q, MT, N);
    // Layer 2: agg = mean relu(z1q[src]+eaq); out = agg@W2l + b2l + z1@W2r (f32)
    aggregate_kernel<<<AGB, 256, 0, stream>>>(z1q, eaq, off, pairsrc, aggb, N);
    gemm_mfma_kernel<0, 0><<<1024, 256, 0, stream>>>(aggb, z1b, Wt2, b2l,
                                                     out, nullptr, nullptr, MT, N);
}